// Round 22
// baseline (98.750 us; speedup 1.0000x reference)
//
#include <hip/hip_runtime.h>
#include <hip/hip_bf16.h>

// Problem constants
#define BSZ 4
#define LSEQ 2048
#define VECD 512
#define NH 8
#define HD 64

typedef __attribute__((ext_vector_type(8))) short bf16x8;
typedef __attribute__((ext_vector_type(4))) short short4v;
typedef __attribute__((ext_vector_type(8))) short short8v;
typedef __attribute__((ext_vector_type(4))) float f32x4;
typedef __attribute__((ext_vector_type(16))) float f32x16;

__device__ inline short f2bf(float f) {
    union { float f; unsigned u; } v; v.f = f;
    unsigned u = v.u;
    u += 0x7fffu + ((u >> 16) & 1u);   // RNE
    return (short)(u >> 16);
}

__device__ inline unsigned cvtpk_bf16(float lo, float hi) {
    unsigned r;
    asm volatile("v_cvt_pk_bf16_f32 %0, %1, %2" : "=v"(r) : "v"(lo), "v"(hi));
    return r;
}

__device__ inline float exp2a(float v) {   // 2^v
    float r;
    asm("v_exp_f32 %0, %1" : "=v"(r) : "v"(v));
    return r;
}

__device__ inline void plswap(unsigned &a, unsigned &b) {
    asm volatile("v_permlane32_swap_b32 %0, %1" : "+v"(a), "+v"(b));
}

__device__ inline void gll16(const void* g, void* l) {
    __builtin_amdgcn_global_load_lds(
        (const __attribute__((address_space(1))) unsigned int*)g,
        (__attribute__((address_space(3))) unsigned int*)l, 16, 0, 0);
}

// ---------------------------------------------------------------------------
// Kernel 0: W -> WT bf16 transpose.  WT[z][(h*64+d)*512 + k] = W_z[h][k][d]
// ---------------------------------------------------------------------------
__launch_bounds__(256)
__global__ void w_kernel(const float* __restrict__ Wq, const float* __restrict__ Wk,
                         const float* __restrict__ Wv, short* __restrict__ WT) {
    __shared__ short T[64][72];
    const int bi = blockIdx.x;
    const int z = bi >> 3, h = bi & 7;
    const float* W = ((z == 0) ? Wq : (z == 1) ? Wk : Wv) + (size_t)h * VECD * HD;
    short* out = WT + (size_t)z * 512 * 512 + (size_t)h * 64 * 512;

    const int tid = threadIdx.x;
    for (int kt = 0; kt < 8; kt++) {
        int k0 = kt * 64;
        int r = tid >> 2, seg = tid & 3;
        for (int j = 0; j < 4; j++) {
            float4 v = *(const float4*)(W + (size_t)(k0 + r) * HD + seg * 16 + j * 4);
            T[seg * 16 + j * 4 + 0][r] = f2bf(v.x);
            T[seg * 16 + j * 4 + 1][r] = f2bf(v.y);
            T[seg * 16 + j * 4 + 2][r] = f2bf(v.z);
            T[seg * 16 + j * 4 + 3][r] = f2bf(v.w);
        }
        __syncthreads();
        int d = tid >> 2, ks = tid & 3;
        *(short8v*)(out + (size_t)d * 512 + k0 + ks * 16) = *(const short8v*)&T[d][ks * 16];
        *(short8v*)(out + (size_t)d * 512 + k0 + ks * 16 + 8) = *(const short8v*)&T[d][ks * 16 + 8];
        __syncthreads();
    }
}

// ---------------------------------------------------------------------------
// Kernel 1: QKV projection GEMM, occupancy-raised: M-tile 64, N-tile 128,
// grid (128,4,3) = 1536 blocks = 6/CU, LDS 24KB -> 24 waves/CU (was 12).
// Single-buffer Bs (dbuf measured null), T14 areg prefetch on A retained.
// Q pre-scaled by 0.125*log2(e); z==2 scaled by vmask and written transposed.
// ---------------------------------------------------------------------------
__launch_bounds__(256, 6)
__global__ void proj_kernel(const float* __restrict__ q_in, const float* __restrict__ k_in,
                            const float* __restrict__ v_in, const short* __restrict__ WT,
                            const float* __restrict__ vmask,
                            short* __restrict__ Qp, short* __restrict__ Kp,
                            short* __restrict__ VpT) {
    __shared__ char psm[24576];                  // As 8K | Bs 16K ; T aliases (18K)
    short* As = (short*)psm;                     // [64][64]
    short* Bs = (short*)(psm + 8192);            // [128][64]
    short* T  = (short*)psm;                     // [128 n][72 pad] epilogue transpose

    const int z  = blockIdx.z;
    const int xb = blockIdx.x;                   // 0..127 (64-row blocks)
    const int n0i = blockIdx.y;

    const float* in = (z == 0) ? q_in : (z == 1) ? k_in : v_in;
    const float sc  = (z == 0) ? 0.18033688011112042f : 1.0f;   // 0.125*log2(e)
    const short* wt = WT + (size_t)z * 512 * 512;

    const int tid  = threadIdx.x;
    const int lane = tid & 63;
    const int w    = tid >> 6;
    const int r0   = xb * 64;
    const int n0   = n0i * 128;

    const int row16 = lane & 15;
    const int grp   = lane >> 4;
    const int wm    = (w >> 1) * 32;             // m-quadrant (32 rows)
    const int wn    = (w & 1) * 64;              // n-quadrant (64 cols)

    f32x4 acc[2][4];
    for (int i = 0; i < 2; i++)
        for (int j = 0; j < 4; j++) acc[i][j] = (f32x4)0.f;

    // T14 prefetch registers for the A tile (4 x float4 = 16 VGPR)
    float4 areg[4];
    #pragma unroll
    for (int i = 0; i < 4; i++) {
        int id2 = tid + 256 * i;
        int m = id2 >> 4, kc4 = id2 & 15;
        areg[i] = *(const float4*)(in + (size_t)(r0 + m) * VECD + kc4 * 4);
    }

    for (int kt = 0; kt < 8; ++kt) {
        const int k0 = kt * 64;
        // convert + write the prefetched A tile (64 x 64)
        #pragma unroll
        for (int i = 0; i < 4; i++) {
            int id2 = tid + 256 * i;
            int m = id2 >> 4, kc4 = id2 & 15;
            int c = kc4 >> 1, half = kc4 & 1;
            uint2 p;
            p.x = cvtpk_bf16(areg[i].x, areg[i].y);
            p.y = cvtpk_bf16(areg[i].z, areg[i].w);
            *(uint2*)&As[m * 64 + (c ^ (m & 7)) * 8 + half * 4] = p;
        }
        // stage B (128 x 64) via gll16, pre-swizzled source, linear dest
        #pragma unroll
        for (int i = 0; i < 4; i++) {
            int id2 = tid + 256 * i;
            int n = id2 >> 3, c = id2 & 7;
            gll16(wt + (size_t)(n0 + n) * 512 + k0 + ((c ^ (n & 7)) * 8),
                  (void*)(Bs + (w * 64 + 256 * i) * 8));
        }
        __syncthreads();   // barrier1: As written; Bs gll16 drained

        // prefetch next A tile during the MFMA phase
        if (kt < 7) {
            #pragma unroll
            for (int i = 0; i < 4; i++) {
                int id2 = tid + 256 * i;
                int m = id2 >> 4, kc4 = id2 & 15;
                areg[i] = *(const float4*)(in + (size_t)(r0 + m) * VECD + k0 + 64 + kc4 * 4);
            }
        }

        for (int kc = 0; kc < 2; kc++) {
            bf16x8 a[2], b[4];
            for (int mt = 0; mt < 2; mt++) {
                int row = wm + mt * 16 + row16;
                int cg = kc * 4 + grp;
                a[mt] = *(const bf16x8*)&As[row * 64 + (cg ^ (row & 7)) * 8];
            }
            for (int nt = 0; nt < 4; nt++) {
                int row = wn + nt * 16 + row16;
                int cg = kc * 4 + grp;
                b[nt] = *(const bf16x8*)&Bs[row * 64 + (cg ^ (row & 7)) * 8];
            }
            for (int mt = 0; mt < 2; mt++)
                for (int nt = 0; nt < 4; nt++)
                    acc[mt][nt] = __builtin_amdgcn_mfma_f32_16x16x32_bf16(a[mt], b[nt], acc[mt][nt], 0, 0, 0);
        }
        __syncthreads();   // barrier2: LDS reads done
    }

    if (z == 2) {
        // V: scale rows by vmask, write transposed through LDS T[128 n][72].
        for (int mt = 0; mt < 2; mt++)
            for (int r = 0; r < 4; r++) {
                int ml = wm + mt * 16 + grp * 4 + r;
                int bl = r0 + ml;
                float vm = vmask[(bl >> 11) * LSEQ + (bl & (LSEQ - 1))];
                for (int nt = 0; nt < 4; nt++) {
                    int nl = wn + nt * 16 + row16;
                    T[nl * 72 + ml] = f2bf(acc[mt][nt][r] * vm);
                }
            }
        __syncthreads();
        const int nl = tid >> 1, half = tid & 1;
        const int n = n0 + nl;
        const int h = n >> 6, d = n & 63;
        const int b = r0 >> 11;
        const int lbase = (r0 & (LSEQ - 1)) + half * 32;
        short* dst = VpT + (((size_t)b * NH + h) * HD + d) * LSEQ + lbase;
        #pragma unroll
        for (int j = 0; j < 4; j++)
            *(short8v*)(dst + j * 8) = *(const short8v*)&T[nl * 72 + half * 32 + j * 8];
    } else {
        short* out = (z == 0) ? Qp : Kp;
        for (int mt = 0; mt < 2; mt++)
            for (int r = 0; r < 4; r++) {
                int m = r0 + wm + mt * 16 + grp * 4 + r;
                int b = m >> 11, l = m & (LSEQ - 1);
                for (int nt = 0; nt < 4; nt++) {
                    int n = n0 + wn + nt * 16 + row16;
                    int h = n >> 6, d = n & 63;
                    out[(((size_t)b * NH + h) * LSEQ + l) * HD + d] = f2bf(acc[mt][nt][r] * sc);
                }
            }
    }
}

// ---------------------------------------------------------------------------
// Kernel 2: attention (round-21, unchanged).  gll16 dbuf staging, ONE barrier
// per K-tile, 32x32x16 MFMA, in-register P, vmask pre-folded into V.
// ---------------------------------------------------------------------------
__launch_bounds__(256, 4)
__global__ void attn_kernel(const short* __restrict__ Qp, const short* __restrict__ Kp,
                            const short* __restrict__ VpT,
                            const float* __restrict__ qmask,
                            short* __restrict__ x) {
    __shared__ char smem[2 * 16384 + 2 * 2 * 32 * 4];
    float* Dd = (float*)(smem + 32768);
    float* Ex = (float*)smem;

    const int tid  = threadIdx.x;
    const int lane = tid & 63;
    const int w    = tid >> 6;
    const int pair = w >> 1;
    const int mh   = w & 1;

    const int ii  = blockIdx.x + 32 * blockIdx.y;
    const int swz = (ii & 7) * 128 + (ii >> 3);
    const int x31 = swz & 31;
    const int bh  = swz >> 5;
    const int b   = bh >> 3;
    const int h   = bh & 7;

    const int t  = (pair == 0) ? x31 : (63 - x31);
    const int kd = t >> 1;
    const int kv = (63 - x31) >> 1;
    const int qbase = t * 32;

    const size_t base   = (size_t)bh * LSEQ * HD;
    const size_t vtbase = (size_t)bh * HD * LSEQ;

    const int l31  = lane & 31;
    const int hsel = lane >> 5;
    const int lq   = qbase + l31;

    bf16x8 q[4];
    #pragma unroll
    for (int ks = 0; ks < 4; ks++)
        q[ks] = *(const bf16x8*)(Qp + base + (size_t)lq * HD + ks * 16 + hsel * 8);

    f32x16 o0 = (f32x16)0.f, o1 = (f32x16)0.f;
    float dsum = 0.f;

    auto stage = [&](int k, int buf) {
        const short* ksrc = Kp + base + (size_t)(k * 64) * HD;
        short* Ksb = (short*)(smem + buf * 16384);
        short* VTb = Ksb + 4096;
        #pragma unroll
        for (int i = 0; i < 2; i++) {
            int id = tid + 256 * i;
            int row = id >> 3, c = id & 7;
            int cs = c ^ (row & 7) ^ ((row >> 3) & 7);
            gll16(ksrc + row * HD + cs * 8, (void*)(Ksb + (w * 64 + 256 * i) * 8));
            if (k <= kv)
                gll16(VpT + vtbase + (size_t)row * LSEQ + k * 64 + cs * 8,
                      (void*)(VTb + (w * 64 + 256 * i) * 8));
        }
    };

    stage(0, 0);

    const int mrow = mh * 32 + l31;
    const int msw  = (mrow & 7) ^ ((mrow >> 3) & 7);

    int cur = 0;
    for (int k = 0; k < 32; ++k) {
        __syncthreads();                 // buf[cur] complete (vmcnt drained)
        if (k < 31) stage(k + 1, cur ^ 1);

        const short* Ks  = (const short*)(smem + cur * 16384);
        const short* VTs = Ks + 4096;

        f32x16 s = (f32x16)0.f;
        bf16x8 kf[4];
        #pragma unroll
        for (int ks = 0; ks < 4; ks++)
            kf[ks] = *(const bf16x8*)&Ks[mrow * 64 + ((ks * 2 + hsel) ^ msw) * 8];
        __builtin_amdgcn_s_setprio(1);
        #pragma unroll
        for (int ks = 0; ks < 4; ks++)
            s = __builtin_amdgcn_mfma_f32_32x32x16_bf16(kf[ks], q[ks], s, 0, 0, 0);
        __builtin_amdgcn_s_setprio(0);

        float e[16];
        #pragma unroll
        for (int r = 0; r < 16; r++) {
            e[r] = exp2a(s[r]);
            dsum += e[r];
        }

        if (k <= kd) {
            if (k == kd) {   // causal select on the diagonal tile only
                #pragma unroll
                for (int g = 0; g < 4; g++) {
                    int mb = k * 64 + mh * 32 + 8 * g + 4 * hsel;
                    e[4 * g + 0] = (mb + 0 <= lq) ? e[4 * g + 0] : 0.f;
                    e[4 * g + 1] = (mb + 1 <= lq) ? e[4 * g + 1] : 0.f;
                    e[4 * g + 2] = (mb + 2 <= lq) ? e[4 * g + 2] : 0.f;
                    e[4 * g + 3] = (mb + 3 <= lq) ? e[4 * g + 3] : 0.f;
                }
            }

            #pragma unroll
            for (int ks2 = 0; ks2 < 2; ks2++) {
                int b0 = 8 * ks2;
                unsigned pk0 = cvtpk_bf16(e[b0 + 0], e[b0 + 1]);
                unsigned pk1 = cvtpk_bf16(e[b0 + 2], e[b0 + 3]);
                unsigned pk2 = cvtpk_bf16(e[b0 + 4], e[b0 + 5]);
                unsigned pk3 = cvtpk_bf16(e[b0 + 6], e[b0 + 7]);
                plswap(pk2, pk0);
                plswap(pk3, pk1);
                union { unsigned u[4]; bf16x8 v; } pu;
                pu.u[0] = pk0; pu.u[1] = pk1; pu.u[2] = pk2; pu.u[3] = pk3;

                int chunk = mh * 4 + ks2 * 2 + hsel;
                bf16x8 vb0, vb1;
                {
                    int drow = l31;
                    vb0 = *(const bf16x8*)&VTs[drow * 64 +
                        ((chunk ^ (drow & 7) ^ ((drow >> 3) & 7))) * 8];
                }
                {
                    int drow = 32 + l31;
                    vb1 = *(const bf16x8*)&VTs[drow * 64 +
                        ((chunk ^ (drow & 7) ^ ((drow >> 3) & 7))) * 8];
                }
                __builtin_amdgcn_s_setprio(1);
                o0 = __builtin_amdgcn_mfma_f32_32x32x16_bf16(pu.v, vb0, o0, 0, 0, 0);
                o1 = __builtin_amdgcn_mfma_f32_32x32x16_bf16(pu.v, vb1, o1, 0, 0, 0);
                __builtin_amdgcn_s_setprio(0);
            }
        }

        cur ^= 1;
    }

    dsum += __shfl_xor(dsum, 32, 64);
    if (lane < 32) Dd[pair * 64 + mh * 32 + l31] = dsum;
    __syncthreads();

    {
        const int wbuf = (pair * 2 + (1 - mh)) * 1024;
        #pragma unroll
        for (int r = 0; r < 16; r++) {
            int ql = (r & 3) + 8 * (r >> 2) + 4 * hsel;
            Ex[wbuf + ql * 32 + l31] = (mh == 0) ? o1[r] : o0[r];
        }
    }
    __syncthreads();

    {
        const int rbuf = (pair * 2 + mh) * 1024;
        #pragma unroll
        for (int r = 0; r < 16; r++) {
            int ql = (r & 3) + 8 * (r >> 2) + 4 * hsel;
            float own = (mh == 0) ? o0[r] : o1[r];
            float val = own + Ex[rbuf + ql * 32 + l31];
            float den = Dd[pair * 64 + ql] + Dd[pair * 64 + 32 + ql];
            int lqr = qbase + ql;
            float inv = qmask[b * LSEQ + lqr] / den;
            x[((size_t)b * LSEQ + lqr) * VECD + h * HD + mh * 32 + l31] = f2bf(val * inv);
        }
    }
}

// ---------------------------------------------------------------------------
// Kernel 3: residual + LayerNorm (eps=1e-3); x is bf16, output f32.
// ---------------------------------------------------------------------------
__launch_bounds__(256)
__global__ void ln_kernel(const short* __restrict__ x, const float* __restrict__ q,
                          const float* __restrict__ gamma, const float* __restrict__ beta,
                          float* __restrict__ out) {
    const int tid  = threadIdx.x;
    const int lane = tid & 63;
    const int w    = tid >> 6;
    const size_t row = (size_t)blockIdx.x * 4 + w;

    short8v xs = *(const short8v*)(x + row * VECD + lane * 8);
    const float* qr = q + row * VECD + lane * 8;
    float4 b0 = *(const float4*)qr;
    float4 b1 = *(const float4*)(qr + 4);
    float xb[8];
    #pragma unroll
    for (int j = 0; j < 8; j++) {
        union { unsigned u; float f; } c; c.u = ((unsigned)(unsigned short)xs[j]) << 16;
        xb[j] = c.f;
    }
    float y[8] = { xb[0] + b0.x, xb[1] + b0.y, xb[2] + b0.z, xb[3] + b0.w,
                   xb[4] + b1.x, xb[5] + b1.y, xb[6] + b1.z, xb[7] + b1.w };

    float s = 0.f;
    for (int j = 0; j < 8; j++) s += y[j];
    for (int off = 1; off < 64; off <<= 1) s += __shfl_xor(s, off, 64);
    float mean = s * (1.f / 512.f);

    float v = 0.f;
    for (int j = 0; j < 8; j++) { float d = y[j] - mean; v += d * d; }
    for (int off = 1; off < 64; off <<= 1) v += __shfl_xor(v, off, 64);
    float inv = rsqrtf(v * (1.f / 512.f) + 1e-3f);

    float4 g0 = *(const float4*)(gamma + lane * 8);
    float4 g1 = *(const float4*)(gamma + lane * 8 + 4);
    float4 e0 = *(const float4*)(beta + lane * 8);
    float4 e1 = *(const float4*)(beta + lane * 8 + 4);

    float4 o0, o1;
    o0.x = (y[0] - mean) * inv * g0.x + e0.x;
    o0.y = (y[1] - mean) * inv * g0.y + e0.y;
    o0.z = (y[2] - mean) * inv * g0.z + e0.z;
    o0.w = (y[3] - mean) * inv * g0.w + e0.w;
    o1.x = (y[4] - mean) * inv * g1.x + e1.x;
    o1.y = (y[5] - mean) * inv * g1.y + e1.y;
    o1.z = (y[6] - mean) * inv * g1.z + e1.z;
    o1.w = (y[7] - mean) * inv * g1.w + e1.w;
    *(float4*)(out + row * VECD + lane * 8) = o0;
    *(float4*)(out + row * VECD + lane * 8 + 4) = o1;
}

// ---------------------------------------------------------------------------
extern "C" void kernel_launch(void* const* d_in, const int* in_sizes, int n_in,
                              void* d_out, int out_size, void* d_ws, size_t ws_size,
                              hipStream_t stream) {
    const float* query = (const float*)d_in[0];
    const float* key   = (const float*)d_in[1];
    const float* value = (const float*)d_in[2];
    const float* qmask = (const float*)d_in[3];
    const float* vmask = (const float*)d_in[4];
    const float* Wq    = (const float*)d_in[5];
    const float* Wk    = (const float*)d_in[6];
    const float* Wv    = (const float*)d_in[7];
    const float* gamma = (const float*)d_in[8];
    const float* beta  = (const float*)d_in[9];

    // ws (bf16 shorts): Qp | Kp | VpT | x | WT   (~35 MB)
    const size_t QKV_ELTS = (size_t)BSZ * NH * LSEQ * HD;   // 4,194,304
    short* Qp  = (short*)d_ws;
    short* Kp  = Qp + QKV_ELTS;
    short* VpT = Kp + QKV_ELTS;
    short* x   = VpT + QKV_ELTS;                    // bf16 [B][L][512]
    short* WT  = x + QKV_ELTS;

    w_kernel<<<24, 256, 0, stream>>>(Wq, Wk, Wv, WT);
    proj_kernel<<<dim3(128, 4, 3), 256, 0, stream>>>(query, key, value, WT, vmask, Qp, Kp, VpT);
    attn_kernel<<<dim3(32, 32), 256, 0, stream>>>(Qp, Kp, VpT, qmask, x);
    ln_kernel<<<2048, 256, 0, stream>>>(x, query, gamma, beta, (float*)d_out);
}

// Round 23
// 85.720 us; speedup vs baseline: 1.1520x; 1.1520x over previous
//
#include <hip/hip_runtime.h>
#include <hip/hip_bf16.h>

// Problem constants
#define BSZ 4
#define LSEQ 2048
#define VECD 512
#define NH 8
#define HD 64

typedef __attribute__((ext_vector_type(8))) short bf16x8;
typedef __attribute__((ext_vector_type(4))) short short4v;
typedef __attribute__((ext_vector_type(8))) short short8v;
typedef __attribute__((ext_vector_type(4))) float f32x4;
typedef __attribute__((ext_vector_type(16))) float f32x16;

__device__ inline short f2bf(float f) {
    union { float f; unsigned u; } v; v.f = f;
    unsigned u = v.u;
    u += 0x7fffu + ((u >> 16) & 1u);   // RNE
    return (short)(u >> 16);
}

__device__ inline unsigned cvtpk_bf16(float lo, float hi) {
    unsigned r;
    asm volatile("v_cvt_pk_bf16_f32 %0, %1, %2" : "=v"(r) : "v"(lo), "v"(hi));
    return r;
}

__device__ inline float exp2a(float v) {   // 2^v
    float r;
    asm("v_exp_f32 %0, %1" : "=v"(r) : "v"(v));
    return r;
}

__device__ inline void plswap(unsigned &a, unsigned &b) {
    asm volatile("v_permlane32_swap_b32 %0, %1" : "+v"(a), "+v"(b));
}

__device__ inline void gll16(const void* g, void* l) {
    __builtin_amdgcn_global_load_lds(
        (const __attribute__((address_space(1))) unsigned int*)g,
        (__attribute__((address_space(3))) unsigned int*)l, 16, 0, 0);
}

// ---------------------------------------------------------------------------
// Kernel 0: W -> WT bf16 transpose.  WT[z][(h*64+d)*512 + k] = W_z[h][k][d]
// ---------------------------------------------------------------------------
__launch_bounds__(256)
__global__ void w_kernel(const float* __restrict__ Wq, const float* __restrict__ Wk,
                         const float* __restrict__ Wv, short* __restrict__ WT) {
    __shared__ short T[64][72];
    const int bi = blockIdx.x;
    const int z = bi >> 3, h = bi & 7;
    const float* W = ((z == 0) ? Wq : (z == 1) ? Wk : Wv) + (size_t)h * VECD * HD;
    short* out = WT + (size_t)z * 512 * 512 + (size_t)h * 64 * 512;

    const int tid = threadIdx.x;
    for (int kt = 0; kt < 8; kt++) {
        int k0 = kt * 64;
        int r = tid >> 2, seg = tid & 3;
        for (int j = 0; j < 4; j++) {
            float4 v = *(const float4*)(W + (size_t)(k0 + r) * HD + seg * 16 + j * 4);
            T[seg * 16 + j * 4 + 0][r] = f2bf(v.x);
            T[seg * 16 + j * 4 + 1][r] = f2bf(v.y);
            T[seg * 16 + j * 4 + 2][r] = f2bf(v.z);
            T[seg * 16 + j * 4 + 3][r] = f2bf(v.w);
        }
        __syncthreads();
        int d = tid >> 2, ks = tid & 3;
        *(short8v*)(out + (size_t)d * 512 + k0 + ks * 16) = *(const short8v*)&T[d][ks * 16];
        *(short8v*)(out + (size_t)d * 512 + k0 + ks * 16 + 8) = *(const short8v*)&T[d][ks * 16 + 8];
        __syncthreads();
    }
}

// ---------------------------------------------------------------------------
// Kernel 1: QKV projection GEMM (round-21 best configuration).  Q pre-scaled
// by 0.125*log2(e).  z==2 (V) scaled by vmask row-wise and written transposed.
// T14 dbuf on both staging paths.  grid (64,4,3), block 256.
// ---------------------------------------------------------------------------
__launch_bounds__(256, 3)
__global__ void proj_kernel(const float* __restrict__ q_in, const float* __restrict__ k_in,
                            const float* __restrict__ v_in, const short* __restrict__ WT,
                            const float* __restrict__ vmask,
                            short* __restrict__ Qp, short* __restrict__ Kp,
                            short* __restrict__ VpT) {
    __shared__ char psm[49152];                  // As 16K | Bs0 16K | Bs1 16K
    short* As = (short*)psm;
    short* T  = (short*)psm;                     // [128 n][136 pad] epilogue transpose

    const int z  = blockIdx.z;
    const int xb = blockIdx.x;
    const int n0i = blockIdx.y;

    const float* in = (z == 0) ? q_in : (z == 1) ? k_in : v_in;
    const float sc  = (z == 0) ? 0.18033688011112042f : 1.0f;   // 0.125*log2(e)
    const short* wt = WT + (size_t)z * 512 * 512;

    const int tid  = threadIdx.x;
    const int lane = tid & 63;
    const int w    = tid >> 6;
    const int r0   = xb * 128;
    const int n0   = n0i * 128;

    const int row16 = lane & 15;
    const int grp   = lane >> 4;
    const int wm    = (w >> 1) * 64;
    const int wn    = (w & 1) * 64;

    f32x4 acc[4][4];
    for (int i = 0; i < 4; i++)
        for (int j = 0; j < 4; j++) acc[i][j] = (f32x4)0.f;

    // T14 prefetch registers for the A tile (8 x float4 = 32 VGPR)
    float4 areg[8];
    #pragma unroll
    for (int i = 0; i < 8; i++) {
        int id2 = tid + 256 * i;
        int m = id2 >> 4, kc4 = id2 & 15;
        areg[i] = *(const float4*)(in + (size_t)(r0 + m) * VECD + kc4 * 4);
    }

    auto stageB = [&](int kt, int buf) {
        short* Bsb = (short*)(psm + 16384 + buf * 16384);
        #pragma unroll
        for (int i = 0; i < 4; i++) {
            int id2 = tid + 256 * i;
            int n = id2 >> 3, c = id2 & 7;
            gll16(wt + (size_t)(n0 + n) * 512 + kt * 64 + ((c ^ (n & 7)) * 8),
                  (void*)(Bsb + (w * 64 + 256 * i) * 8));
        }
    };

    stageB(0, 0);

    for (int kt = 0; kt < 8; ++kt) {
        const int buf = kt & 1;
        #pragma unroll
        for (int i = 0; i < 8; i++) {
            int id2 = tid + 256 * i;
            int m = id2 >> 4, kc4 = id2 & 15;
            int c = kc4 >> 1, half = kc4 & 1;
            uint2 p;
            p.x = cvtpk_bf16(areg[i].x, areg[i].y);
            p.y = cvtpk_bf16(areg[i].z, areg[i].w);
            *(uint2*)&As[m * 64 + (c ^ (m & 7)) * 8 + half * 4] = p;
        }
        __syncthreads();   // barrier1: As writes done; Bs[buf] gll16 drained

        if (kt < 7) {
            stageB(kt + 1, buf ^ 1);
            #pragma unroll
            for (int i = 0; i < 8; i++) {
                int id2 = tid + 256 * i;
                int m = id2 >> 4, kc4 = id2 & 15;
                areg[i] = *(const float4*)(in + (size_t)(r0 + m) * VECD + (kt + 1) * 64 + kc4 * 4);
            }
        }

        const short* Bs = (const short*)(psm + 16384 + buf * 16384);
        for (int kc = 0; kc < 2; kc++) {
            bf16x8 a[4], b[4];
            for (int mt = 0; mt < 4; mt++) {
                int row = wm + mt * 16 + row16;
                int cg = kc * 4 + grp;
                a[mt] = *(const bf16x8*)&As[row * 64 + (cg ^ (row & 7)) * 8];
            }
            for (int nt = 0; nt < 4; nt++) {
                int row = wn + nt * 16 + row16;
                int cg = kc * 4 + grp;
                b[nt] = *(const bf16x8*)&Bs[row * 64 + (cg ^ (row & 7)) * 8];
            }
            for (int mt = 0; mt < 4; mt++)
                for (int nt = 0; nt < 4; nt++)
                    acc[mt][nt] = __builtin_amdgcn_mfma_f32_16x16x32_bf16(a[mt], b[nt], acc[mt][nt], 0, 0, 0);
        }
        __syncthreads();   // barrier2: As reads done (also drains prefetches)
    }

    if (z == 2) {
        // V: scale rows by vmask, write transposed through LDS.
        for (int mt = 0; mt < 4; mt++)
            for (int r = 0; r < 4; r++) {
                int ml = wm + mt * 16 + grp * 4 + r;
                int bl = r0 + ml;
                float vm = vmask[(bl >> 11) * LSEQ + (bl & (LSEQ - 1))];
                for (int nt = 0; nt < 4; nt++) {
                    int nl = wn + nt * 16 + row16;
                    T[nl * 136 + ml] = f2bf(acc[mt][nt][r] * vm);
                }
            }
        __syncthreads();
        const int nl = tid >> 1, half = tid & 1;
        const int n = n0 + nl;
        const int h = n >> 6, d = n & 63;
        const int b = r0 >> 11;
        const int lbase = (r0 & (LSEQ - 1)) + half * 64;
        short* dst = VpT + (((size_t)b * NH + h) * HD + d) * LSEQ + lbase;
        #pragma unroll
        for (int j = 0; j < 8; j++)
            *(short8v*)(dst + j * 8) = *(const short8v*)&T[nl * 136 + half * 64 + j * 8];
    } else {
        short* out = (z == 0) ? Qp : Kp;
        for (int mt = 0; mt < 4; mt++)
            for (int r = 0; r < 4; r++) {
                int m = r0 + wm + mt * 16 + grp * 4 + r;
                int b = m >> 11, l = m & (LSEQ - 1);
                for (int nt = 0; nt < 4; nt++) {
                    int n = n0 + wn + nt * 16 + row16;
                    int h = n >> 6, d = n & 63;
                    out[(((size_t)b * NH + h) * LSEQ + l) * HD + d] = f2bf(acc[mt][nt][r] * sc);
                }
            }
    }
}

// ---------------------------------------------------------------------------
// Kernel 2: attention (round-21).  vmask pre-folded into V; PV masking is
// the diagonal-tile causal select only.  gll16 double-buffer staging, ONE
// barrier per K-tile, 32x32x16 MFMA, in-register P.  grid (32,32), block 256.
// ---------------------------------------------------------------------------
__launch_bounds__(256, 4)
__global__ void attn_kernel(const short* __restrict__ Qp, const short* __restrict__ Kp,
                            const short* __restrict__ VpT,
                            const float* __restrict__ qmask,
                            short* __restrict__ x) {
    __shared__ char smem[2 * 16384 + 2 * 2 * 32 * 4];
    float* Dd = (float*)(smem + 32768);
    float* Ex = (float*)smem;

    const int tid  = threadIdx.x;
    const int lane = tid & 63;
    const int w    = tid >> 6;
    const int pair = w >> 1;
    const int mh   = w & 1;

    const int ii  = blockIdx.x + 32 * blockIdx.y;
    const int swz = (ii & 7) * 128 + (ii >> 3);
    const int x31 = swz & 31;
    const int bh  = swz >> 5;
    const int b   = bh >> 3;
    const int h   = bh & 7;

    const int t  = (pair == 0) ? x31 : (63 - x31);
    const int kd = t >> 1;
    const int kv = (63 - x31) >> 1;
    const int qbase = t * 32;

    const size_t base   = (size_t)bh * LSEQ * HD;
    const size_t vtbase = (size_t)bh * HD * LSEQ;

    const int l31  = lane & 31;
    const int hsel = lane >> 5;
    const int lq   = qbase + l31;

    bf16x8 q[4];
    #pragma unroll
    for (int ks = 0; ks < 4; ks++)
        q[ks] = *(const bf16x8*)(Qp + base + (size_t)lq * HD + ks * 16 + hsel * 8);

    f32x16 o0 = (f32x16)0.f, o1 = (f32x16)0.f;
    float dsum = 0.f;

    auto stage = [&](int k, int buf) {
        const short* ksrc = Kp + base + (size_t)(k * 64) * HD;
        short* Ksb = (short*)(smem + buf * 16384);
        short* VTb = Ksb + 4096;
        #pragma unroll
        for (int i = 0; i < 2; i++) {
            int id = tid + 256 * i;
            int row = id >> 3, c = id & 7;
            int cs = c ^ (row & 7) ^ ((row >> 3) & 7);
            gll16(ksrc + row * HD + cs * 8, (void*)(Ksb + (w * 64 + 256 * i) * 8));
            if (k <= kv)
                gll16(VpT + vtbase + (size_t)row * LSEQ + k * 64 + cs * 8,
                      (void*)(VTb + (w * 64 + 256 * i) * 8));
        }
    };

    stage(0, 0);

    const int mrow = mh * 32 + l31;
    const int msw  = (mrow & 7) ^ ((mrow >> 3) & 7);

    int cur = 0;
    for (int k = 0; k < 32; ++k) {
        __syncthreads();                 // buf[cur] complete (vmcnt drained)
        if (k < 31) stage(k + 1, cur ^ 1);

        const short* Ks  = (const short*)(smem + cur * 16384);
        const short* VTs = Ks + 4096;

        f32x16 s = (f32x16)0.f;
        bf16x8 kf[4];
        #pragma unroll
        for (int ks = 0; ks < 4; ks++)
            kf[ks] = *(const bf16x8*)&Ks[mrow * 64 + ((ks * 2 + hsel) ^ msw) * 8];
        __builtin_amdgcn_s_setprio(1);
        #pragma unroll
        for (int ks = 0; ks < 4; ks++)
            s = __builtin_amdgcn_mfma_f32_32x32x16_bf16(kf[ks], q[ks], s, 0, 0, 0);
        __builtin_amdgcn_s_setprio(0);

        float e[16];
        #pragma unroll
        for (int r = 0; r < 16; r++) {
            e[r] = exp2a(s[r]);
            dsum += e[r];
        }

        if (k <= kd) {
            if (k == kd) {   // causal select on the diagonal tile only
                #pragma unroll
                for (int g = 0; g < 4; g++) {
                    int mb = k * 64 + mh * 32 + 8 * g + 4 * hsel;
                    e[4 * g + 0] = (mb + 0 <= lq) ? e[4 * g + 0] : 0.f;
                    e[4 * g + 1] = (mb + 1 <= lq) ? e[4 * g + 1] : 0.f;
                    e[4 * g + 2] = (mb + 2 <= lq) ? e[4 * g + 2] : 0.f;
                    e[4 * g + 3] = (mb + 3 <= lq) ? e[4 * g + 3] : 0.f;
                }
            }

            #pragma unroll
            for (int ks2 = 0; ks2 < 2; ks2++) {
                int b0 = 8 * ks2;
                unsigned pk0 = cvtpk_bf16(e[b0 + 0], e[b0 + 1]);
                unsigned pk1 = cvtpk_bf16(e[b0 + 2], e[b0 + 3]);
                unsigned pk2 = cvtpk_bf16(e[b0 + 4], e[b0 + 5]);
                unsigned pk3 = cvtpk_bf16(e[b0 + 6], e[b0 + 7]);
                plswap(pk2, pk0);
                plswap(pk3, pk1);
                union { unsigned u[4]; bf16x8 v; } pu;
                pu.u[0] = pk0; pu.u[1] = pk1; pu.u[2] = pk2; pu.u[3] = pk3;

                int chunk = mh * 4 + ks2 * 2 + hsel;
                bf16x8 vb0, vb1;
                {
                    int drow = l31;
                    vb0 = *(const bf16x8*)&VTs[drow * 64 +
                        ((chunk ^ (drow & 7) ^ ((drow >> 3) & 7))) * 8];
                }
                {
                    int drow = 32 + l31;
                    vb1 = *(const bf16x8*)&VTs[drow * 64 +
                        ((chunk ^ (drow & 7) ^ ((drow >> 3) & 7))) * 8];
                }
                __builtin_amdgcn_s_setprio(1);
                o0 = __builtin_amdgcn_mfma_f32_32x32x16_bf16(pu.v, vb0, o0, 0, 0, 0);
                o1 = __builtin_amdgcn_mfma_f32_32x32x16_bf16(pu.v, vb1, o1, 0, 0, 0);
                __builtin_amdgcn_s_setprio(0);
            }
        }

        cur ^= 1;
    }

    dsum += __shfl_xor(dsum, 32, 64);
    if (lane < 32) Dd[pair * 64 + mh * 32 + l31] = dsum;
    __syncthreads();

    {
        const int wbuf = (pair * 2 + (1 - mh)) * 1024;
        #pragma unroll
        for (int r = 0; r < 16; r++) {
            int ql = (r & 3) + 8 * (r >> 2) + 4 * hsel;
            Ex[wbuf + ql * 32 + l31] = (mh == 0) ? o1[r] : o0[r];
        }
    }
    __syncthreads();

    {
        const int rbuf = (pair * 2 + mh) * 1024;
        #pragma unroll
        for (int r = 0; r < 16; r++) {
            int ql = (r & 3) + 8 * (r >> 2) + 4 * hsel;
            float own = (mh == 0) ? o0[r] : o1[r];
            float val = own + Ex[rbuf + ql * 32 + l31];
            float den = Dd[pair * 64 + ql] + Dd[pair * 64 + 32 + ql];
            int lqr = qbase + ql;
            float inv = qmask[b * LSEQ + lqr] / den;
            x[((size_t)b * LSEQ + lqr) * VECD + h * HD + mh * 32 + l31] = f2bf(val * inv);
        }
    }
}

// ---------------------------------------------------------------------------
// Kernel 3: residual + LayerNorm (eps=1e-3); x is bf16, output f32.
// ---------------------------------------------------------------------------
__launch_bounds__(256)
__global__ void ln_kernel(const short* __restrict__ x, const float* __restrict__ q,
                          const float* __restrict__ gamma, const float* __restrict__ beta,
                          float* __restrict__ out) {
    const int tid  = threadIdx.x;
    const int lane = tid & 63;
    const int w    = tid >> 6;
    const size_t row = (size_t)blockIdx.x * 4 + w;

    short8v xs = *(const short8v*)(x + row * VECD + lane * 8);
    const float* qr = q + row * VECD + lane * 8;
    float4 b0 = *(const float4*)qr;
    float4 b1 = *(const float4*)(qr + 4);
    float xb[8];
    #pragma unroll
    for (int j = 0; j < 8; j++) {
        union { unsigned u; float f; } c; c.u = ((unsigned)(unsigned short)xs[j]) << 16;
        xb[j] = c.f;
    }
    float y[8] = { xb[0] + b0.x, xb[1] + b0.y, xb[2] + b0.z, xb[3] + b0.w,
                   xb[4] + b1.x, xb[5] + b1.y, xb[6] + b1.z, xb[7] + b1.w };

    float s = 0.f;
    for (int j = 0; j < 8; j++) s += y[j];
    for (int off = 1; off < 64; off <<= 1) s += __shfl_xor(s, off, 64);
    float mean = s * (1.f / 512.f);

    float v = 0.f;
    for (int j = 0; j < 8; j++) { float d = y[j] - mean; v += d * d; }
    for (int off = 1; off < 64; off <<= 1) v += __shfl_xor(v, off, 64);
    float inv = rsqrtf(v * (1.f / 512.f) + 1e-3f);

    float4 g0 = *(const float4*)(gamma + lane * 8);
    float4 g1 = *(const float4*)(gamma + lane * 8 + 4);
    float4 e0 = *(const float4*)(beta + lane * 8);
    float4 e1 = *(const float4*)(beta + lane * 8 + 4);

    float4 o0, o1;
    o0.x = (y[0] - mean) * inv * g0.x + e0.x;
    o0.y = (y[1] - mean) * inv * g0.y + e0.y;
    o0.z = (y[2] - mean) * inv * g0.z + e0.z;
    o0.w = (y[3] - mean) * inv * g0.w + e0.w;
    o1.x = (y[4] - mean) * inv * g1.x + e1.x;
    o1.y = (y[5] - mean) * inv * g1.y + e1.y;
    o1.z = (y[6] - mean) * inv * g1.z + e1.z;
    o1.w = (y[7] - mean) * inv * g1.w + e1.w;
    *(float4*)(out + row * VECD + lane * 8) = o0;
    *(float4*)(out + row * VECD + lane * 8 + 4) = o1;
}

// ---------------------------------------------------------------------------
extern "C" void kernel_launch(void* const* d_in, const int* in_sizes, int n_in,
                              void* d_out, int out_size, void* d_ws, size_t ws_size,
                              hipStream_t stream) {
    const float* query = (const float*)d_in[0];
    const float* key   = (const float*)d_in[1];
    const float* value = (const float*)d_in[2];
    const float* qmask = (const float*)d_in[3];
    const float* vmask = (const float*)d_in[4];
    const float* Wq    = (const float*)d_in[5];
    const float* Wk    = (const float*)d_in[6];
    const float* Wv    = (const float*)d_in[7];
    const float* gamma = (const float*)d_in[8];
    const float* beta  = (const float*)d_in[9];

    // ws (bf16 shorts): Qp | Kp | VpT | x | WT   (~35 MB)
    const size_t QKV_ELTS = (size_t)BSZ * NH * LSEQ * HD;   // 4,194,304
    short* Qp  = (short*)d_ws;
    short* Kp  = Qp + QKV_ELTS;
    short* VpT = Kp + QKV_ELTS;
    short* x   = VpT + QKV_ELTS;                    // bf16 [B][L][512]
    short* WT  = x + QKV_ELTS;

    w_kernel<<<24, 256, 0, stream>>>(Wq, Wk, Wv, WT);
    proj_kernel<<<dim3(64, 4, 3), 256, 0, stream>>>(query, key, value, WT, vmask, Qp, Kp, VpT);
    attn_kernel<<<dim3(32, 32), 256, 0, stream>>>(Qp, Kp, VpT, qmask, x);
    ln_kernel<<<2048, 256, 0, stream>>>(x, query, gamma, beta, (float*)d_out);
}